// Round 1
// baseline (1066.656 us; speedup 1.0000x reference)
//
#include <hip/hip_runtime.h>
#include <math.h>

#define NNODES 20000
#define NEDGES 320000
#define FDIM 64
#define NHEAD 4
#define NGR 64
#define LATD 512
#define HF 256               // NHEAD*FDIM
#define NEP (NEDGES + NNODES) // edges incl. self loops = 340000
#define AGGIN 832            // FDIM*(1+3*NHEAD)

// ---------------- encode: n0 = relu(sf@sW.T+sb)*smask + relu(bf@bW.T+bb)*bmask ----
__global__ __launch_bounds__(256) void encode_n0(
    const float* __restrict__ sfeat, const float* __restrict__ bfeat,
    const float* __restrict__ smask, const float* __restrict__ bmask,
    const float* __restrict__ sW, const float* __restrict__ sb,
    const float* __restrict__ bW, const float* __restrict__ bb,
    float* __restrict__ n0)
{
    int t = blockIdx.x * 256 + threadIdx.x;
    if (t >= NNODES * FDIM) return;
    int node = t >> 6;
    int f = t & 63;
    const float4* x4 = (const float4*)(sfeat + (size_t)node * 128);
    const float4* w4 = (const float4*)(sW + (size_t)f * 128);
    float acc = 0.f;
#pragma unroll
    for (int k = 0; k < 32; k++) {
        float4 a = x4[k], b = w4[k];
        acc += a.x * b.x + a.y * b.y + a.z * b.z + a.w * b.w;
    }
    float sv = fmaxf(acc + sb[f], 0.f);
    float accb = 0.f;
#pragma unroll
    for (int k = 0; k < 5; k++) accb += bfeat[node * 5 + k] * bW[f * 5 + k];
    float bv = fmaxf(accb + bb[f], 0.f);
    n0[(size_t)node * FDIM + f] = sv * smask[node] + bv * bmask[node];
}

// ---------------- CSR build ----------------
__global__ void count_deg(const int* __restrict__ ei, int* __restrict__ cnt)
{
    int i = blockIdx.x * 256 + threadIdx.x;
    if (i < NEDGES) {
        atomicAdd(&cnt[ei[NEDGES + i]], 1);
    } else if (i < NEP) {
        atomicAdd(&cnt[i - NEDGES], 1); // self loop
    }
}

__global__ __launch_bounds__(256) void scan_deg(const int* __restrict__ deg, int* __restrict__ offs)
{
    __shared__ int sums[256];
    const int per = (NNODES + 255) / 256;
    int t = threadIdx.x;
    int start = t * per;
    int end = start + per; if (end > NNODES) end = NNODES;
    int s = 0;
    for (int i = start; i < end && i < NNODES; i++) s += deg[i];
    sums[t] = s;
    __syncthreads();
    if (t == 0) {
        int acc = 0;
        for (int i = 0; i < 256; i++) { int v = sums[i]; sums[i] = acc; acc += v; }
    }
    __syncthreads();
    int acc = sums[t];
    for (int i = start; i < end && i < NNODES; i++) { offs[i] = acc; acc += deg[i]; }
    if (t == 255) offs[NNODES] = NEP;
}

__global__ void scatter_edges(const int* __restrict__ ei, const int* __restrict__ offs,
                              int* __restrict__ cnt, int* __restrict__ csr_src)
{
    int i = blockIdx.x * 256 + threadIdx.x;
    if (i < NEDGES) {
        int dv = ei[NEDGES + i];
        int p = offs[dv] + atomicAdd(&cnt[dv], 1);
        csr_src[p] = ei[i];
    } else if (i < NEP) {
        int nv = i - NEDGES;
        int p = offs[nv] + atomicAdd(&cnt[nv], 1);
        csr_src[p] = nv;
    }
}

// ---------------- GEMM + attention projections ----------------
// h[n][o] = sum_k x[n][k]*W[o][k]; s[n][hd] = sum_f h[n][hd*64+f]*a_src[hd][f]; same d.
// Block: 256 thr = 4 waves; block covers 16 nodes x 256 outputs.
// Wave w: nodes nbase..nbase+3 (nbase = blk*16 + 4w). Thread: 4 nodes x 4 outputs
// with o = lane + 64*j (j = head index).
template <int IN>
__global__ __launch_bounds__(256) void gemm_attn(
    const float* __restrict__ x, const float* __restrict__ W,
    const float* __restrict__ a_src, const float* __restrict__ a_dst,
    float* __restrict__ h, float* __restrict__ s, float* __restrict__ d)
{
    __shared__ float wlds[256 * 36]; // 36-float padded rows (16B-aligned, uniform banks)
    int t = threadIdx.x;
    int lane = t & 63;
    int wave = t >> 6;
    int nbase = blockIdx.x * 16 + wave * 4;

    float acc[4][4];
#pragma unroll
    for (int i = 0; i < 4; i++)
#pragma unroll
        for (int j = 0; j < 4; j++) acc[i][j] = 0.f;

    const float* xrow0 = x + (size_t)nbase * IN;

    for (int kc = 0; kc < IN; kc += 32) {
        __syncthreads();
        // stage W[0:256][kc:kc+32] into LDS, coalesced
#pragma unroll
        for (int it = 0; it < 8; it++) {
            int idx = it * 256 + t;
            int o = idx >> 3, f4 = idx & 7;
            float4 v = *(const float4*)(W + (size_t)o * IN + kc + f4 * 4);
            *(float4*)(&wlds[o * 36 + f4 * 4]) = v;
        }
        __syncthreads();
#pragma unroll
        for (int k4 = 0; k4 < 8; k4++) {
            float4 xv[4];
#pragma unroll
            for (int i = 0; i < 4; i++)
                xv[i] = *(const float4*)(xrow0 + (size_t)i * IN + kc + k4 * 4);
#pragma unroll
            for (int j = 0; j < 4; j++) {
                float4 wv = *(const float4*)(&wlds[(lane + 64 * j) * 36 + k4 * 4]);
#pragma unroll
                for (int i = 0; i < 4; i++)
                    acc[i][j] += xv[i].x * wv.x + xv[i].y * wv.y + xv[i].z * wv.z + xv[i].w * wv.w;
            }
        }
    }

    // write h
#pragma unroll
    for (int i = 0; i < 4; i++)
#pragma unroll
        for (int j = 0; j < 4; j++)
            h[(size_t)(nbase + i) * HF + lane + 64 * j] = acc[i][j];

    // attention projections: per-lane partials then 64-lane butterfly
    float ps[4][4], pd[4][4];
#pragma unroll
    for (int j = 0; j < 4; j++) {
        float as = a_src[j * 64 + lane];
        float ad = a_dst[j * 64 + lane];
#pragma unroll
        for (int i = 0; i < 4; i++) {
            ps[i][j] = acc[i][j] * as;
            pd[i][j] = acc[i][j] * ad;
        }
    }
#pragma unroll
    for (int m = 1; m < 64; m <<= 1) {
#pragma unroll
        for (int i = 0; i < 4; i++)
#pragma unroll
            for (int j = 0; j < 4; j++) {
                ps[i][j] += __shfl_xor(ps[i][j], m, 64);
                pd[i][j] += __shfl_xor(pd[i][j], m, 64);
            }
    }
    if (lane == 0) {
#pragma unroll
        for (int i = 0; i < 4; i++)
#pragma unroll
            for (int j = 0; j < 4; j++) {
                s[(size_t)(nbase + i) * NHEAD + j] = ps[i][j];
                d[(size_t)(nbase + i) * NHEAD + j] = pd[i][j];
            }
    }
}

// ---------------- GAT softmax + aggregate (one wave per node) ----------------
__global__ __launch_bounds__(256) void gat_aggr(
    const float* __restrict__ h, const float* __restrict__ s, const float* __restrict__ d,
    const int* __restrict__ offs, const int* __restrict__ csr_src,
    const float* __restrict__ bias, float* __restrict__ out)
{
    int t = threadIdx.x;
    int lane = t & 63;
    int wave = t >> 6;
    int node = blockIdx.x * 4 + wave;
    int head = lane >> 4;

    float dn = d[(size_t)node * NHEAD + head];
    int lo = offs[node], hi = offs[node + 1];

    float mx = -3.402823466e38f;
    for (int i = lo; i < hi; i++) {
        int src = csr_src[i];
        float e = s[(size_t)src * NHEAD + head] + dn;
        e = fmaxf(e, 0.2f * e); // leaky_relu 0.2
        mx = fmaxf(mx, e);
    }
    float den = 0.f;
    float a0 = 0.f, a1 = 0.f, a2 = 0.f, a3 = 0.f;
    for (int i = lo; i < hi; i++) {
        int src = csr_src[i];
        float e = s[(size_t)src * NHEAD + head] + dn;
        e = fmaxf(e, 0.2f * e);
        float ex = __expf(e - mx);
        den += ex;
        float4 hv = *(const float4*)(h + (size_t)src * HF + lane * 4);
        a0 += ex * hv.x; a1 += ex * hv.y; a2 += ex * hv.z; a3 += ex * hv.w;
    }
    float inv = 1.f / den;
    int o0 = lane * 4;
    float4 r;
    r.x = fmaxf(a0 * inv + bias[o0 + 0], 0.f);
    r.y = fmaxf(a1 * inv + bias[o0 + 1], 0.f);
    r.z = fmaxf(a2 * inv + bias[o0 + 2], 0.f);
    r.w = fmaxf(a3 * inv + bias[o0 + 3], 0.f);
    *(float4*)(out + (size_t)node * HF + o0) = r;
}

// ---------------- per-graph segment max (batch is sorted) ----------------
__global__ __launch_bounds__(256) void seg_max(
    const float* __restrict__ x, const int* __restrict__ batch, int C,
    float* __restrict__ g, int coloff)
{
    __shared__ int slo, shi;
    int gi = blockIdx.x;
    if (threadIdx.x == 0) {
        int lo = 0, hi = NNODES;
        while (lo < hi) { int mid = (lo + hi) >> 1; if (batch[mid] < gi) lo = mid + 1; else hi = mid; }
        slo = lo;
        int lo2 = 0, hi2 = NNODES;
        while (lo2 < hi2) { int mid = (lo2 + hi2) >> 1; if (batch[mid] < gi + 1) lo2 = mid + 1; else hi2 = mid; }
        shi = lo2;
    }
    __syncthreads();
    int lo = slo, hi = shi;
    for (int f = threadIdx.x; f < C; f += 256) {
        float m = -3.402823466e38f;
        for (int nd = lo; nd < hi; nd++)
            m = fmaxf(m, x[(size_t)nd * C + f]);
        g[(size_t)gi * AGGIN + coloff + f] = m;
    }
}

// ---------------- MLP head ----------------
__global__ __launch_bounds__(256) void mlp_latent(
    const float* __restrict__ g, const float* __restrict__ W, const float* __restrict__ b,
    float* __restrict__ latent)
{
    int idx = blockIdx.x * 256 + threadIdx.x; // 64*512
    int r = idx >> 9, c = idx & 511;
    const float4* gv = (const float4*)(g + (size_t)r * AGGIN);
    const float4* wv = (const float4*)(W + (size_t)c * AGGIN);
    float acc = 0.f;
#pragma unroll 4
    for (int k = 0; k < AGGIN / 4; k++) {
        float4 a = gv[k], w = wv[k];
        acc += a.x * w.x + a.y * w.y + a.z * w.z + a.w * w.w;
    }
    latent[idx] = acc + b[c];
}

__global__ __launch_bounds__(256) void mlp_head(
    const float* __restrict__ latent,
    const float* __restrict__ muW, const float* __restrict__ mub,
    const float* __restrict__ vW, const float* __restrict__ vb,
    float* __restrict__ out)
{
    int idx = blockIdx.x * 256 + threadIdx.x; // 2*64*512
    int half = idx >> 15;
    int j = idx & 32767;
    int r = j >> 9, c = j & 511;
    const float* W = half ? vW : muW;
    const float* bb = half ? vb : mub;
    const float4* lv = (const float4*)(latent + (size_t)r * LATD);
    const float4* wv = (const float4*)(W + (size_t)c * LATD);
    float acc = 0.f;
#pragma unroll 4
    for (int k = 0; k < LATD / 4; k++) {
        float4 a = lv[k], w = wv[k];
        acc += a.x * w.x + a.y * w.y + a.z * w.z + a.w * w.w;
    }
    out[idx] = acc + bb[c];
}

// ---------------- launch ----------------
static inline size_t align16(size_t x) { return (x + 15) & ~(size_t)15; }

extern "C" void kernel_launch(void* const* d_in, const int* in_sizes, int n_in,
                              void* d_out, int out_size, void* d_ws, size_t ws_size,
                              hipStream_t stream)
{
    const float* sfeat = (const float*)d_in[0];
    const float* bfeat = (const float*)d_in[1];
    const float* smask = (const float*)d_in[2];
    const float* bmask = (const float*)d_in[3];
    const int*   ei    = (const int*)d_in[4];
    const int*   batch = (const int*)d_in[5];
    const float* sW = (const float*)d_in[6];
    const float* sb = (const float*)d_in[7];
    const float* bW = (const float*)d_in[8];
    const float* bb = (const float*)d_in[9];
    const float* W1 = (const float*)d_in[10];
    const float* as1 = (const float*)d_in[11];
    const float* ad1 = (const float*)d_in[12];
    const float* b1 = (const float*)d_in[13];
    const float* W2 = (const float*)d_in[14];
    const float* as2 = (const float*)d_in[15];
    const float* ad2 = (const float*)d_in[16];
    const float* b2 = (const float*)d_in[17];
    const float* W3 = (const float*)d_in[18];
    const float* as3 = (const float*)d_in[19];
    const float* ad3 = (const float*)d_in[20];
    const float* b3 = (const float*)d_in[21];
    const float* aggW = (const float*)d_in[22];
    const float* aggb = (const float*)d_in[23];
    const float* muW = (const float*)d_in[24];
    const float* mub = (const float*)d_in[25];
    const float* vW = (const float*)d_in[26];
    const float* vb = (const float*)d_in[27];
    float* out = (float*)d_out;

    char* ws = (char*)d_ws;
    size_t off = 0;
    float* n0 = (float*)(ws + off); off = align16(off + (size_t)NNODES * FDIM * 4);
    float* h  = (float*)(ws + off); off = align16(off + (size_t)NNODES * HF * 4);
    float* xA = (float*)(ws + off); off = align16(off + (size_t)NNODES * HF * 4);
    float* xB = (float*)(ws + off); off = align16(off + (size_t)NNODES * HF * 4);
    float* s  = (float*)(ws + off); off = align16(off + (size_t)NNODES * NHEAD * 4);
    float* d  = (float*)(ws + off); off = align16(off + (size_t)NNODES * NHEAD * 4);
    int* offs = (int*)(ws + off);   off = align16(off + (size_t)(NNODES + 1) * 4);
    int* cnt  = (int*)(ws + off);   off = align16(off + (size_t)NNODES * 4);
    int* csr  = (int*)(ws + off);   off = align16(off + (size_t)NEP * 4);
    float* g  = (float*)(ws + off); off = align16(off + (size_t)NGR * AGGIN * 4);
    float* lat = (float*)(ws + off); off = align16(off + (size_t)NGR * LATD * 4);

    const int edgeBlocks = (NEP + 255) / 256;

    // CSR build
    hipMemsetAsync(cnt, 0, (size_t)NNODES * 4, stream);
    count_deg<<<edgeBlocks, 256, 0, stream>>>(ei, cnt);
    scan_deg<<<1, 256, 0, stream>>>(cnt, offs);
    hipMemsetAsync(cnt, 0, (size_t)NNODES * 4, stream);
    scatter_edges<<<edgeBlocks, 256, 0, stream>>>(ei, offs, cnt, csr);

    // node encoder
    encode_n0<<<(NNODES * FDIM + 255) / 256, 256, 0, stream>>>(
        sfeat, bfeat, smask, bmask, sW, sb, bW, bb, n0);
    seg_max<<<NGR, 256, 0, stream>>>(n0, batch, FDIM, g, 0);

    // layer 1
    gemm_attn<FDIM><<<NNODES / 16, 256, 0, stream>>>(n0, W1, as1, ad1, h, s, d);
    gat_aggr<<<NNODES / 4, 256, 0, stream>>>(h, s, d, offs, csr, b1, xA);
    seg_max<<<NGR, 256, 0, stream>>>(xA, batch, HF, g, FDIM);

    // layer 2
    gemm_attn<HF><<<NNODES / 16, 256, 0, stream>>>(xA, W2, as2, ad2, h, s, d);
    gat_aggr<<<NNODES / 4, 256, 0, stream>>>(h, s, d, offs, csr, b2, xB);
    seg_max<<<NGR, 256, 0, stream>>>(xB, batch, HF, g, FDIM + HF);

    // layer 3
    gemm_attn<HF><<<NNODES / 16, 256, 0, stream>>>(xB, W3, as3, ad3, h, s, d);
    gat_aggr<<<NNODES / 4, 256, 0, stream>>>(h, s, d, offs, csr, b3, xA);
    seg_max<<<NGR, 256, 0, stream>>>(xA, batch, HF, g, FDIM + 2 * HF);

    // MLP head
    mlp_latent<<<(NGR * LATD + 255) / 256, 256, 0, stream>>>(g, aggW, aggb, lat);
    mlp_head<<<(2 * NGR * LATD + 255) / 256, 256, 0, stream>>>(lat, muW, mub, vW, vb, out);
}

// Round 2
// 742.067 us; speedup vs baseline: 1.4374x; 1.4374x over previous
//
#include <hip/hip_runtime.h>
#include <math.h>

#define NNODES 20000
#define NEDGES 320000
#define FDIM 64
#define NHEAD 4
#define NGR 64
#define LATD 512
#define HF 256               // NHEAD*FDIM
#define NEP (NEDGES + NNODES) // edges incl. self loops = 340000
#define AGGIN 832            // FDIM*(1+3*NHEAD)

// ---------------- encode: n0 = relu(sf@sW.T+sb)*smask + relu(bf@bW.T+bb)*bmask ----
// Block: 256 thr = 4 waves; each wave handles 8 nodes x 64 features (block: 32 nodes).
// sW staged in LDS with 132-float padded rows (bank stride 4 -> 8-way on b128, ~3x,
// vs 64 L1 cache lines per wave-load in the naive per-lane-row version).
__global__ __launch_bounds__(256) void encode_n0(
    const float* __restrict__ sfeat, const float* __restrict__ bfeat,
    const float* __restrict__ smask, const float* __restrict__ bmask,
    const float* __restrict__ sW, const float* __restrict__ sb,
    const float* __restrict__ bW, const float* __restrict__ bb,
    float* __restrict__ n0)
{
    __shared__ float wlds[64 * 132];
    int t = threadIdx.x;
    // stage sW [64][128] -> [64][132]
#pragma unroll
    for (int it = 0; it < 8; it++) {
        int idx = it * 256 + t;       // 2048 float4s
        int f = idx >> 5, k4 = idx & 31;
        float4 v = *(const float4*)(sW + f * 128 + k4 * 4);
        *(float4*)(&wlds[f * 132 + k4 * 4]) = v;
    }
    __syncthreads();

    int lane = t & 63, wave = t >> 6;
    int nb = blockIdx.x * 32 + wave * 8;

    float acc[8];
#pragma unroll
    for (int i = 0; i < 8; i++) acc[i] = 0.f;

    const float* xbase = sfeat + (size_t)nb * 128;
    for (int k4 = 0; k4 < 32; k4++) {
        float4 wv = *(const float4*)(&wlds[lane * 132 + k4 * 4]);
#pragma unroll
        for (int i = 0; i < 8; i++) {
            float4 xv = *(const float4*)(xbase + i * 128 + k4 * 4); // broadcast, L1
            acc[i] += xv.x * wv.x + xv.y * wv.y + xv.z * wv.z + xv.w * wv.w;
        }
    }

    float bwr[5];
#pragma unroll
    for (int k = 0; k < 5; k++) bwr[k] = bW[lane * 5 + k];
    float sbv = sb[lane], bbv = bb[lane];

#pragma unroll
    for (int i = 0; i < 8; i++) {
        int node = nb + i;
        float accb = 0.f;
#pragma unroll
        for (int k = 0; k < 5; k++) accb += bfeat[node * 5 + k] * bwr[k];
        float sv = fmaxf(acc[i] + sbv, 0.f);
        float bv = fmaxf(accb + bbv, 0.f);
        n0[(size_t)node * FDIM + lane] = sv * smask[node] + bv * bmask[node];
    }
}

// ---------------- CSR build ----------------
__global__ void count_deg(const int* __restrict__ ei, int* __restrict__ cnt)
{
    int i = blockIdx.x * 256 + threadIdx.x;
    if (i < NEDGES) {
        atomicAdd(&cnt[ei[NEDGES + i]], 1);
    } else if (i < NEP) {
        atomicAdd(&cnt[i - NEDGES], 1); // self loop
    }
}

__global__ __launch_bounds__(256) void scan_deg(const int* __restrict__ deg, int* __restrict__ offs)
{
    __shared__ int sums[256];
    const int per = (NNODES + 255) / 256;
    int t = threadIdx.x;
    int start = t * per;
    int end = start + per; if (end > NNODES) end = NNODES;
    int s = 0;
    for (int i = start; i < end && i < NNODES; i++) s += deg[i];
    sums[t] = s;
    __syncthreads();
    if (t == 0) {
        int acc = 0;
        for (int i = 0; i < 256; i++) { int v = sums[i]; sums[i] = acc; acc += v; }
    }
    __syncthreads();
    int acc = sums[t];
    for (int i = start; i < end && i < NNODES; i++) { offs[i] = acc; acc += deg[i]; }
    if (t == 255) offs[NNODES] = NEP;
}

__global__ void scatter_edges(const int* __restrict__ ei, const int* __restrict__ offs,
                              int* __restrict__ cnt, int* __restrict__ csr_src)
{
    int i = blockIdx.x * 256 + threadIdx.x;
    if (i < NEDGES) {
        int dv = ei[NEDGES + i];
        int p = offs[dv] + atomicAdd(&cnt[dv], 1);
        csr_src[p] = ei[i];
    } else if (i < NEP) {
        int nv = i - NEDGES;
        int p = offs[nv] + atomicAdd(&cnt[nv], 1);
        csr_src[p] = nv;
    }
}

// ---------------- GEMM + attention projections ----------------
template <int IN>
__global__ __launch_bounds__(256) void gemm_attn(
    const float* __restrict__ x, const float* __restrict__ W,
    const float* __restrict__ a_src, const float* __restrict__ a_dst,
    float* __restrict__ h, float* __restrict__ s, float* __restrict__ d)
{
    __shared__ float wlds[256 * 36]; // 36-float padded rows
    int t = threadIdx.x;
    int lane = t & 63;
    int wave = t >> 6;
    int nbase = blockIdx.x * 16 + wave * 4;

    float acc[4][4];
#pragma unroll
    for (int i = 0; i < 4; i++)
#pragma unroll
        for (int j = 0; j < 4; j++) acc[i][j] = 0.f;

    const float* xrow0 = x + (size_t)nbase * IN;

    for (int kc = 0; kc < IN; kc += 32) {
        __syncthreads();
#pragma unroll
        for (int it = 0; it < 8; it++) {
            int idx = it * 256 + t;
            int o = idx >> 3, f4 = idx & 7;
            float4 v = *(const float4*)(W + (size_t)o * IN + kc + f4 * 4);
            *(float4*)(&wlds[o * 36 + f4 * 4]) = v;
        }
        __syncthreads();
#pragma unroll
        for (int k4 = 0; k4 < 8; k4++) {
            float4 xv[4];
#pragma unroll
            for (int i = 0; i < 4; i++)
                xv[i] = *(const float4*)(xrow0 + (size_t)i * IN + kc + k4 * 4);
#pragma unroll
            for (int j = 0; j < 4; j++) {
                float4 wv = *(const float4*)(&wlds[(lane + 64 * j) * 36 + k4 * 4]);
#pragma unroll
                for (int i = 0; i < 4; i++)
                    acc[i][j] += xv[i].x * wv.x + xv[i].y * wv.y + xv[i].z * wv.z + xv[i].w * wv.w;
            }
        }
    }

#pragma unroll
    for (int i = 0; i < 4; i++)
#pragma unroll
        for (int j = 0; j < 4; j++)
            h[(size_t)(nbase + i) * HF + lane + 64 * j] = acc[i][j];

    float ps[4][4], pd[4][4];
#pragma unroll
    for (int j = 0; j < 4; j++) {
        float as = a_src[j * 64 + lane];
        float ad = a_dst[j * 64 + lane];
#pragma unroll
        for (int i = 0; i < 4; i++) {
            ps[i][j] = acc[i][j] * as;
            pd[i][j] = acc[i][j] * ad;
        }
    }
#pragma unroll
    for (int m = 1; m < 64; m <<= 1) {
#pragma unroll
        for (int i = 0; i < 4; i++)
#pragma unroll
            for (int j = 0; j < 4; j++) {
                ps[i][j] += __shfl_xor(ps[i][j], m, 64);
                pd[i][j] += __shfl_xor(pd[i][j], m, 64);
            }
    }
    if (lane == 0) {
#pragma unroll
        for (int i = 0; i < 4; i++)
#pragma unroll
            for (int j = 0; j < 4; j++) {
                s[(size_t)(nbase + i) * NHEAD + j] = ps[i][j];
                d[(size_t)(nbase + i) * NHEAD + j] = pd[i][j];
            }
    }
}

// ---------------- GAT softmax + aggregate (one wave per node) ----------------
__global__ __launch_bounds__(256) void gat_aggr(
    const float* __restrict__ h, const float* __restrict__ s, const float* __restrict__ d,
    const int* __restrict__ offs, const int* __restrict__ csr_src,
    const float* __restrict__ bias, float* __restrict__ out)
{
    int t = threadIdx.x;
    int lane = t & 63;
    int wave = t >> 6;
    int node = blockIdx.x * 4 + wave;
    int head = lane >> 4;

    float dn = d[(size_t)node * NHEAD + head];
    int lo = offs[node], hi = offs[node + 1];

    float mx = -3.402823466e38f;
    for (int i = lo; i < hi; i++) {
        int src = csr_src[i];
        float e = s[(size_t)src * NHEAD + head] + dn;
        e = fmaxf(e, 0.2f * e); // leaky_relu 0.2
        mx = fmaxf(mx, e);
    }
    float den = 0.f;
    float a0 = 0.f, a1 = 0.f, a2 = 0.f, a3 = 0.f;
    for (int i = lo; i < hi; i++) {
        int src = csr_src[i];
        float e = s[(size_t)src * NHEAD + head] + dn;
        e = fmaxf(e, 0.2f * e);
        float ex = __expf(e - mx);
        den += ex;
        float4 hv = *(const float4*)(h + (size_t)src * HF + lane * 4);
        a0 += ex * hv.x; a1 += ex * hv.y; a2 += ex * hv.z; a3 += ex * hv.w;
    }
    float inv = 1.f / den;
    int o0 = lane * 4;
    float4 r;
    r.x = fmaxf(a0 * inv + bias[o0 + 0], 0.f);
    r.y = fmaxf(a1 * inv + bias[o0 + 1], 0.f);
    r.z = fmaxf(a2 * inv + bias[o0 + 2], 0.f);
    r.w = fmaxf(a3 * inv + bias[o0 + 3], 0.f);
    *(float4*)(out + (size_t)node * HF + o0) = r;
}

// ---------------- per-graph segment max, slab-parallel atomic version ----------
// All pooled inputs are >= 0 (post-ReLU), so float-bits-as-int atomicMax is
// order-correct and zero-init is safe. One team of C threads covers 64
// contiguous rows; flush an atomic only at graph boundaries.
template <int C>
__global__ __launch_bounds__(256) void seg_max_slab(
    const float* __restrict__ x, const int* __restrict__ batch,
    int* __restrict__ g, int coloff)
{
    constexpr int TEAMS = 256 / C;  // 4 for C=64, 1 for C=256
    constexpr int ROWS = 64;
    int team = threadIdx.x / C;
    int f = threadIdx.x % C;
    int r0 = (blockIdx.x * TEAMS + team) * ROWS;
    if (r0 >= NNODES) return;
    int r1 = r0 + ROWS; if (r1 > NNODES) r1 = NNODES;
    int cur = batch[r0];
    float m = 0.f;
    for (int r = r0; r < r1; r++) {
        int b = batch[r];
        if (b != cur) {
            atomicMax(&g[cur * AGGIN + coloff + f], __float_as_int(m));
            m = 0.f; cur = b;
        }
        m = fmaxf(m, x[(size_t)r * C + f]);
    }
    atomicMax(&g[cur * AGGIN + coloff + f], __float_as_int(m));
}

// ---------------- MLP head ----------------
__global__ __launch_bounds__(256) void mlp_latent(
    const float* __restrict__ g, const float* __restrict__ W, const float* __restrict__ b,
    float* __restrict__ latent)
{
    int idx = blockIdx.x * 256 + threadIdx.x; // 64*512
    int r = idx >> 9, c = idx & 511;
    const float4* gv = (const float4*)(g + (size_t)r * AGGIN);
    const float4* wv = (const float4*)(W + (size_t)c * AGGIN);
    float acc = 0.f;
#pragma unroll 4
    for (int k = 0; k < AGGIN / 4; k++) {
        float4 a = gv[k], w = wv[k];
        acc += a.x * w.x + a.y * w.y + a.z * w.z + a.w * w.w;
    }
    latent[idx] = acc + b[c];
}

__global__ __launch_bounds__(256) void mlp_head(
    const float* __restrict__ latent,
    const float* __restrict__ muW, const float* __restrict__ mub,
    const float* __restrict__ vW, const float* __restrict__ vb,
    float* __restrict__ out)
{
    int idx = blockIdx.x * 256 + threadIdx.x; // 2*64*512
    int half = idx >> 15;
    int j = idx & 32767;
    int r = j >> 9, c = j & 511;
    const float* W = half ? vW : muW;
    const float* bb = half ? vb : mub;
    const float4* lv = (const float4*)(latent + (size_t)r * LATD);
    const float4* wv = (const float4*)(W + (size_t)c * LATD);
    float acc = 0.f;
#pragma unroll 4
    for (int k = 0; k < LATD / 4; k++) {
        float4 a = lv[k], w = wv[k];
        acc += a.x * w.x + a.y * w.y + a.z * w.z + a.w * w.w;
    }
    out[idx] = acc + bb[c];
}

// ---------------- launch ----------------
static inline size_t align16(size_t x) { return (x + 15) & ~(size_t)15; }

extern "C" void kernel_launch(void* const* d_in, const int* in_sizes, int n_in,
                              void* d_out, int out_size, void* d_ws, size_t ws_size,
                              hipStream_t stream)
{
    const float* sfeat = (const float*)d_in[0];
    const float* bfeat = (const float*)d_in[1];
    const float* smask = (const float*)d_in[2];
    const float* bmask = (const float*)d_in[3];
    const int*   ei    = (const int*)d_in[4];
    const int*   batch = (const int*)d_in[5];
    const float* sW = (const float*)d_in[6];
    const float* sb = (const float*)d_in[7];
    const float* bW = (const float*)d_in[8];
    const float* bb = (const float*)d_in[9];
    const float* W1 = (const float*)d_in[10];
    const float* as1 = (const float*)d_in[11];
    const float* ad1 = (const float*)d_in[12];
    const float* b1 = (const float*)d_in[13];
    const float* W2 = (const float*)d_in[14];
    const float* as2 = (const float*)d_in[15];
    const float* ad2 = (const float*)d_in[16];
    const float* b2 = (const float*)d_in[17];
    const float* W3 = (const float*)d_in[18];
    const float* as3 = (const float*)d_in[19];
    const float* ad3 = (const float*)d_in[20];
    const float* b3 = (const float*)d_in[21];
    const float* aggW = (const float*)d_in[22];
    const float* aggb = (const float*)d_in[23];
    const float* muW = (const float*)d_in[24];
    const float* mub = (const float*)d_in[25];
    const float* vW = (const float*)d_in[26];
    const float* vb = (const float*)d_in[27];
    float* out = (float*)d_out;

    char* ws = (char*)d_ws;
    size_t off = 0;
    float* n0 = (float*)(ws + off); off = align16(off + (size_t)NNODES * FDIM * 4);
    float* h  = (float*)(ws + off); off = align16(off + (size_t)NNODES * HF * 4);
    float* xA = (float*)(ws + off); off = align16(off + (size_t)NNODES * HF * 4);
    float* xB = (float*)(ws + off); off = align16(off + (size_t)NNODES * HF * 4);
    float* s  = (float*)(ws + off); off = align16(off + (size_t)NNODES * NHEAD * 4);
    float* d  = (float*)(ws + off); off = align16(off + (size_t)NNODES * NHEAD * 4);
    int* offs = (int*)(ws + off);   off = align16(off + (size_t)(NNODES + 1) * 4);
    int* cnt  = (int*)(ws + off);   off = align16(off + (size_t)NNODES * 4);
    int* csr  = (int*)(ws + off);   off = align16(off + (size_t)NEP * 4);
    float* g  = (float*)(ws + off); off = align16(off + (size_t)NGR * AGGIN * 4);
    float* lat = (float*)(ws + off); off = align16(off + (size_t)NGR * LATD * 4);

    const int edgeBlocks = (NEP + 255) / 256;

    // CSR build
    hipMemsetAsync(cnt, 0, (size_t)NNODES * 4, stream);
    count_deg<<<edgeBlocks, 256, 0, stream>>>(ei, cnt);
    scan_deg<<<1, 256, 0, stream>>>(cnt, offs);
    hipMemsetAsync(cnt, 0, (size_t)NNODES * 4, stream);
    scatter_edges<<<edgeBlocks, 256, 0, stream>>>(ei, offs, cnt, csr);

    // g starts at 0 (all pooled values >= 0)
    hipMemsetAsync(g, 0, (size_t)NGR * AGGIN * 4, stream);

    // node encoder
    encode_n0<<<NNODES / 32, 256, 0, stream>>>(
        sfeat, bfeat, smask, bmask, sW, sb, bW, bb, n0);
    seg_max_slab<FDIM><<<(NNODES + 255) / 256, 256, 0, stream>>>(n0, batch, (int*)g, 0);

    // layer 1
    gemm_attn<FDIM><<<NNODES / 16, 256, 0, stream>>>(n0, W1, as1, ad1, h, s, d);
    gat_aggr<<<NNODES / 4, 256, 0, stream>>>(h, s, d, offs, csr, b1, xA);
    seg_max_slab<HF><<<(NNODES + 63) / 64, 256, 0, stream>>>(xA, batch, (int*)g, FDIM);

    // layer 2
    gemm_attn<HF><<<NNODES / 16, 256, 0, stream>>>(xA, W2, as2, ad2, h, s, d);
    gat_aggr<<<NNODES / 4, 256, 0, stream>>>(h, s, d, offs, csr, b2, xB);
    seg_max_slab<HF><<<(NNODES + 63) / 64, 256, 0, stream>>>(xB, batch, (int*)g, FDIM + HF);

    // layer 3
    gemm_attn<HF><<<NNODES / 16, 256, 0, stream>>>(xB, W3, as3, ad3, h, s, d);
    gat_aggr<<<NNODES / 4, 256, 0, stream>>>(h, s, d, offs, csr, b3, xA);
    seg_max_slab<HF><<<(NNODES + 63) / 64, 256, 0, stream>>>(xA, batch, (int*)g, FDIM + 2 * HF);

    // MLP head
    mlp_latent<<<(NGR * LATD + 255) / 256, 256, 0, stream>>>(g, aggW, aggb, lat);
    mlp_head<<<(2 * NGR * LATD + 255) / 256, 256, 0, stream>>>(lat, muW, mub, vW, vb, out);
}

// Round 3
// 572.950 us; speedup vs baseline: 1.8617x; 1.2952x over previous
//
#include <hip/hip_runtime.h>
#include <math.h>

#define NNODES 20000
#define NEDGES 320000
#define FDIM 64
#define NHEAD 4
#define NGR 64
#define LATD 512
#define HF 256                // NHEAD*FDIM
#define NEP (NEDGES + NNODES) // edges incl. self loops = 340000
#define AGGIN 832             // FDIM*(1+3*NHEAD)
#define MPAD 20032            // 313*64 node padding for 64-row gemm blocks

typedef float f32x4 __attribute__((ext_vector_type(4)));
typedef short bf16x8 __attribute__((ext_vector_type(8)));

__device__ inline unsigned short f2bf(float f) {
    unsigned u = __float_as_uint(f);
    unsigned r = (u + 0x7FFF + ((u >> 16) & 1)) >> 16; // RNE
    return (unsigned short)r;
}
__device__ inline float bf2f(unsigned short h) {
    return __uint_as_float(((unsigned)h) << 16);
}

// ---------------- weight fp32 -> bf16 hi/lo split ----------------
__global__ __launch_bounds__(256) void convert_w(
    const float* __restrict__ src, unsigned short* __restrict__ hi,
    unsigned short* __restrict__ lo, int n)
{
    int i = blockIdx.x * 256 + threadIdx.x;
    if (i < n) {
        float f = src[i];
        unsigned short h = f2bf(f);
        hi[i] = h;
        lo[i] = f2bf(f - bf2f(h));
    }
}

// ---------------- encode: n0 = relu(sf@sW.T)*smask + relu(bf@bW.T)*bmask ------
// also emits bf16 hi/lo copy of n0 (leading dim 64) for the MFMA gemm.
__global__ __launch_bounds__(256) void encode_n0(
    const float* __restrict__ sfeat, const float* __restrict__ bfeat,
    const float* __restrict__ smask, const float* __restrict__ bmask,
    const float* __restrict__ sW, const float* __restrict__ sb,
    const float* __restrict__ bW, const float* __restrict__ bb,
    float* __restrict__ n0, unsigned short* __restrict__ nhi,
    unsigned short* __restrict__ nlo)
{
    __shared__ float wlds[64 * 132];
    int t = threadIdx.x;
#pragma unroll
    for (int it = 0; it < 8; it++) {
        int idx = it * 256 + t;
        int f = idx >> 5, k4 = idx & 31;
        float4 v = *(const float4*)(sW + f * 128 + k4 * 4);
        *(float4*)(&wlds[f * 132 + k4 * 4]) = v;
    }
    __syncthreads();

    int lane = t & 63, wave = t >> 6;
    int nb = blockIdx.x * 32 + wave * 8;

    float acc[8];
#pragma unroll
    for (int i = 0; i < 8; i++) acc[i] = 0.f;

    const float* xbase = sfeat + (size_t)nb * 128;
    for (int k4 = 0; k4 < 32; k4++) {
        float4 wv = *(const float4*)(&wlds[lane * 132 + k4 * 4]);
#pragma unroll
        for (int i = 0; i < 8; i++) {
            float4 xv = *(const float4*)(xbase + i * 128 + k4 * 4);
            acc[i] += xv.x * wv.x + xv.y * wv.y + xv.z * wv.z + xv.w * wv.w;
        }
    }

    float bwr[5];
#pragma unroll
    for (int k = 0; k < 5; k++) bwr[k] = bW[lane * 5 + k];
    float sbv = sb[lane], bbv = bb[lane];

#pragma unroll
    for (int i = 0; i < 8; i++) {
        int node = nb + i;
        float accb = 0.f;
#pragma unroll
        for (int k = 0; k < 5; k++) accb += bfeat[node * 5 + k] * bwr[k];
        float sv = fmaxf(acc[i] + sbv, 0.f);
        float bv = fmaxf(accb + bbv, 0.f);
        float val = sv * smask[node] + bv * bmask[node];
        n0[(size_t)node * FDIM + lane] = val;
        unsigned short hb = f2bf(val);
        nhi[(size_t)node * FDIM + lane] = hb;
        nlo[(size_t)node * FDIM + lane] = f2bf(val - bf2f(hb));
    }
}

// ---------------- CSR build ----------------
__global__ void count_deg(const int* __restrict__ ei, int* __restrict__ cnt)
{
    int i = blockIdx.x * 256 + threadIdx.x;
    if (i < NEDGES) {
        atomicAdd(&cnt[ei[NEDGES + i]], 1);
    } else if (i < NEP) {
        atomicAdd(&cnt[i - NEDGES], 1); // self loop
    }
}

__global__ __launch_bounds__(256) void scan_deg(const int* __restrict__ deg, int* __restrict__ offs)
{
    __shared__ int sums[256];
    const int per = (NNODES + 255) / 256;
    int t = threadIdx.x;
    int start = t * per;
    int end = start + per; if (end > NNODES) end = NNODES;
    int s = 0;
    for (int i = start; i < end && i < NNODES; i++) s += deg[i];
    sums[t] = s;
    __syncthreads();
    if (t == 0) {
        int acc = 0;
        for (int i = 0; i < 256; i++) { int v = sums[i]; sums[i] = acc; acc += v; }
    }
    __syncthreads();
    int acc = sums[t];
    for (int i = start; i < end && i < NNODES; i++) { offs[i] = acc; acc += deg[i]; }
    if (t == 255) offs[NNODES] = NEP;
}

__global__ void scatter_edges(const int* __restrict__ ei, const int* __restrict__ offs,
                              int* __restrict__ cnt, int* __restrict__ csr_src)
{
    int i = blockIdx.x * 256 + threadIdx.x;
    if (i < NEDGES) {
        int dv = ei[NEDGES + i];
        int p = offs[dv] + atomicAdd(&cnt[dv], 1);
        csr_src[p] = ei[i];
    } else if (i < NEP) {
        int nv = i - NEDGES;
        int p = offs[nv] + atomicAdd(&cnt[nv], 1);
        csr_src[p] = nv;
    }
}

// ---------------- MFMA GEMM + attention projections (bf16x3 split) ------------
// D = x @ W.T : M=64 nodes/block, N=256 outputs, K templated (64 or 256).
// Block 256 thr = 4 waves; wave w owns output cols [w*64, w*64+64) = head w,
// all 64 nodes (4 m-tiles x 4 n-tiles of 16x16, mfma_f32_16x16x32_bf16).
// Split product: x_hi*W_hi + x_hi*W_lo + x_lo*W_hi (error ~2^-18, fp32-class).
template <int K>
__global__ __launch_bounds__(256, 3) void gemm_attn_mfma(
    const unsigned short* __restrict__ xhi, const unsigned short* __restrict__ xlo,
    const unsigned short* __restrict__ Whi, const unsigned short* __restrict__ Wlo,
    const float* __restrict__ a_src, const float* __restrict__ a_dst,
    float* __restrict__ h, float* __restrict__ s, float* __restrict__ d)
{
    __shared__ unsigned short wsh_hi[256 * 40];
    __shared__ unsigned short wsh_lo[256 * 40];
    __shared__ unsigned short xsh_hi[64 * 40];
    __shared__ unsigned short xsh_lo[64 * 40];

    int t = threadIdx.x, lane = t & 63, w = t >> 6;
    int colid = lane & 15, quad = lane >> 4;
    int nb = blockIdx.x * 64;

    f32x4 acc[4][4];
#pragma unroll
    for (int mt = 0; mt < 4; mt++)
#pragma unroll
        for (int nt = 0; nt < 4; nt++)
#pragma unroll
            for (int r = 0; r < 4; r++) acc[mt][nt][r] = 0.f;

    for (int kc = 0; kc < K; kc += 32) {
        __syncthreads();
        // stage W[0:256][kc:kc+32] hi+lo, 40-elem padded rows (2-way banks = free)
#pragma unroll
        for (int it = 0; it < 4; it++) {
            int seg = it * 256 + t;           // 1024 16B segments
            int row = seg >> 2, q = seg & 3;
            *(bf16x8*)&wsh_hi[row * 40 + q * 8] =
                *(const bf16x8*)&Whi[(size_t)row * K + kc + q * 8];
            *(bf16x8*)&wsh_lo[row * 40 + q * 8] =
                *(const bf16x8*)&Wlo[(size_t)row * K + kc + q * 8];
        }
        {
            int row = t >> 2, q = t & 3;       // 64 rows x 4 segs
            *(bf16x8*)&xsh_hi[row * 40 + q * 8] =
                *(const bf16x8*)&xhi[(size_t)(nb + row) * K + kc + q * 8];
            *(bf16x8*)&xsh_lo[row * 40 + q * 8] =
                *(const bf16x8*)&xlo[(size_t)(nb + row) * K + kc + q * 8];
        }
        __syncthreads();

        bf16x8 bhi[4], blo[4];
#pragma unroll
        for (int nt = 0; nt < 4; nt++) {
            int brow = w * 64 + nt * 16 + colid;
            bhi[nt] = *(const bf16x8*)&wsh_hi[brow * 40 + quad * 8];
            blo[nt] = *(const bf16x8*)&wsh_lo[brow * 40 + quad * 8];
        }
#pragma unroll
        for (int mt = 0; mt < 4; mt++) {
            int arow = mt * 16 + colid;
            bf16x8 ahi = *(const bf16x8*)&xsh_hi[arow * 40 + quad * 8];
            bf16x8 alo = *(const bf16x8*)&xsh_lo[arow * 40 + quad * 8];
#pragma unroll
            for (int nt = 0; nt < 4; nt++) {
                acc[mt][nt] = __builtin_amdgcn_mfma_f32_16x16x32_bf16(ahi, bhi[nt], acc[mt][nt], 0, 0, 0);
                acc[mt][nt] = __builtin_amdgcn_mfma_f32_16x16x32_bf16(ahi, blo[nt], acc[mt][nt], 0, 0, 0);
                acc[mt][nt] = __builtin_amdgcn_mfma_f32_16x16x32_bf16(alo, bhi[nt], acc[mt][nt], 0, 0, 0);
            }
        }
    }

    // ---- write h: C/D layout row=quad*4+r (node), col=lane&15 (output) ----
#pragma unroll
    for (int mt = 0; mt < 4; mt++) {
#pragma unroll
        for (int r = 0; r < 4; r++) {
            int node = nb + mt * 16 + quad * 4 + r;
            if (node < NNODES) {
#pragma unroll
                for (int nt = 0; nt < 4; nt++)
                    h[(size_t)node * HF + w * 64 + nt * 16 + colid] = acc[mt][nt][r];
            }
        }
    }

    // ---- attention projections for head w ----
    float as_r[4], ad_r[4];
#pragma unroll
    for (int nt = 0; nt < 4; nt++) {
        as_r[nt] = a_src[w * 64 + nt * 16 + colid];
        ad_r[nt] = a_dst[w * 64 + nt * 16 + colid];
    }
#pragma unroll
    for (int mt = 0; mt < 4; mt++) {
#pragma unroll
        for (int r = 0; r < 4; r++) {
            float ps = 0.f, pd = 0.f;
#pragma unroll
            for (int nt = 0; nt < 4; nt++) {
                ps += acc[mt][nt][r] * as_r[nt];
                pd += acc[mt][nt][r] * ad_r[nt];
            }
#pragma unroll
            for (int m = 1; m < 16; m <<= 1) {
                ps += __shfl_xor(ps, m, 64);
                pd += __shfl_xor(pd, m, 64);
            }
            if (colid == 0) {
                int node = nb + mt * 16 + quad * 4 + r;
                if (node < NNODES) {
                    s[(size_t)node * NHEAD + w] = ps;
                    d[(size_t)node * NHEAD + w] = pd;
                }
            }
        }
    }
}

// ---------------- GAT softmax + aggregate (one wave per node) ----------------
// Fast path (deg<=64): phase A edge-parallel (lane=(slot,head)), butterfly
// max/den, exp in registers; phase B feature-parallel with shuffle handoff.
// Also emits bf16 hi/lo of the output (next layer's gemm input) when requested.
__global__ __launch_bounds__(256) void gat_aggr(
    const float* __restrict__ h, const float* __restrict__ s, const float* __restrict__ d,
    const int* __restrict__ offs, const int* __restrict__ csr_src,
    const float* __restrict__ bias, float* __restrict__ out,
    unsigned short* __restrict__ ohi, unsigned short* __restrict__ olo)
{
    int t = threadIdx.x;
    int lane = t & 63;
    int wv = t >> 6;
    int node = blockIdx.x * 4 + wv;
    int head4 = lane >> 4;   // phase-B head
    int lo = offs[node], hi = offs[node + 1];
    int deg = hi - lo;

    float a0 = 0.f, a1 = 0.f, a2 = 0.f, a3 = 0.f;
    float inv;

    if (deg <= 64) {
        int slot = lane >> 2, hd = lane & 3;
        float dn = d[(size_t)node * NHEAD + hd];
        float ev[4];
        int sv[4];
#pragma unroll
        for (int c = 0; c < 4; c++) {
            int k = c * 16 + slot;
            float e = -3.402823466e38f;
            int src = 0;
            if (k < deg) {
                src = csr_src[lo + k];
                float ee = s[(size_t)src * NHEAD + hd] + dn;
                e = fmaxf(ee, 0.2f * ee);
            }
            ev[c] = e; sv[c] = src;
        }
        float mx = fmaxf(fmaxf(ev[0], ev[1]), fmaxf(ev[2], ev[3]));
#pragma unroll
        for (int m = 4; m < 64; m <<= 1) mx = fmaxf(mx, __shfl_xor(mx, m, 64));
        float den = 0.f;
#pragma unroll
        for (int c = 0; c < 4; c++) {
            ev[c] = __expf(ev[c] - mx);  // invalid slots -> exp(-huge) = 0
            den += ev[c];
        }
#pragma unroll
        for (int m = 4; m < 64; m <<= 1) den += __shfl_xor(den, m, 64);

        inv = 1.f / __shfl(den, head4);  // lane 'head4' has hd == head4

        // phase B: feature-parallel gather
#pragma unroll
        for (int c = 0; c < 4; c++) {
            int base = c * 16;
            if (base >= deg) break;
            int n16 = deg - base; if (n16 > 16) n16 = 16;
            for (int k = 0; k < n16; k++) {
                float ex = __shfl(ev[c], k * 4 + head4);
                int src = __shfl(sv[c], k * 4 + head4);
                float4 hv = *(const float4*)(h + (size_t)src * HF + lane * 4);
                a0 += ex * hv.x; a1 += ex * hv.y; a2 += ex * hv.z; a3 += ex * hv.w;
            }
        }
    } else {
        // fallback: serial two-pass (deg > 64; astronomically rare, exact)
        float dn = d[(size_t)node * NHEAD + head4];
        float mx = -3.402823466e38f;
        for (int i = lo; i < hi; i++) {
            int src = csr_src[i];
            float e = s[(size_t)src * NHEAD + head4] + dn;
            e = fmaxf(e, 0.2f * e);
            mx = fmaxf(mx, e);
        }
        float den = 0.f;
        for (int i = lo; i < hi; i++) {
            int src = csr_src[i];
            float e = s[(size_t)src * NHEAD + head4] + dn;
            e = fmaxf(e, 0.2f * e);
            float ex = __expf(e - mx);
            den += ex;
            float4 hv = *(const float4*)(h + (size_t)src * HF + lane * 4);
            a0 += ex * hv.x; a1 += ex * hv.y; a2 += ex * hv.z; a3 += ex * hv.w;
        }
        inv = 1.f / den;
    }

    int o0 = lane * 4;
    float4 r;
    r.x = fmaxf(a0 * inv + bias[o0 + 0], 0.f);
    r.y = fmaxf(a1 * inv + bias[o0 + 1], 0.f);
    r.z = fmaxf(a2 * inv + bias[o0 + 2], 0.f);
    r.w = fmaxf(a3 * inv + bias[o0 + 3], 0.f);
    *(float4*)(out + (size_t)node * HF + o0) = r;

    if (ohi) {
        ushort4 hb, lb;
        hb.x = f2bf(r.x); lb.x = f2bf(r.x - bf2f(hb.x));
        hb.y = f2bf(r.y); lb.y = f2bf(r.y - bf2f(hb.y));
        hb.z = f2bf(r.z); lb.z = f2bf(r.z - bf2f(hb.z));
        hb.w = f2bf(r.w); lb.w = f2bf(r.w - bf2f(hb.w));
        *(ushort4*)(ohi + (size_t)node * HF + o0) = hb;
        *(ushort4*)(olo + (size_t)node * HF + o0) = lb;
    }
}

// ---------------- per-graph segment max, slab-parallel atomic version ----------
template <int C>
__global__ __launch_bounds__(256) void seg_max_slab(
    const float* __restrict__ x, const int* __restrict__ batch,
    int* __restrict__ g, int coloff)
{
    constexpr int TEAMS = 256 / C;
    constexpr int ROWS = 64;
    int team = threadIdx.x / C;
    int f = threadIdx.x % C;
    int r0 = (blockIdx.x * TEAMS + team) * ROWS;
    if (r0 >= NNODES) return;
    int r1 = r0 + ROWS; if (r1 > NNODES) r1 = NNODES;
    int cur = batch[r0];
    float m = 0.f;
    for (int r = r0; r < r1; r++) {
        int b = batch[r];
        if (b != cur) {
            atomicMax(&g[cur * AGGIN + coloff + f], __float_as_int(m));
            m = 0.f; cur = b;
        }
        m = fmaxf(m, x[(size_t)r * C + f]);
    }
    atomicMax(&g[cur * AGGIN + coloff + f], __float_as_int(m));
}

// ---------------- MLP head ----------------
__global__ __launch_bounds__(256) void mlp_latent(
    const float* __restrict__ g, const float* __restrict__ W, const float* __restrict__ b,
    float* __restrict__ latent)
{
    int idx = blockIdx.x * 256 + threadIdx.x; // 64*512
    int r = idx >> 9, c = idx & 511;
    const float4* gv = (const float4*)(g + (size_t)r * AGGIN);
    const float4* wv = (const float4*)(W + (size_t)c * AGGIN);
    float acc = 0.f;
#pragma unroll 4
    for (int k = 0; k < AGGIN / 4; k++) {
        float4 a = gv[k], w = wv[k];
        acc += a.x * w.x + a.y * w.y + a.z * w.z + a.w * w.w;
    }
    latent[idx] = acc + b[c];
}

__global__ __launch_bounds__(256) void mlp_head(
    const float* __restrict__ latent,
    const float* __restrict__ muW, const float* __restrict__ mub,
    const float* __restrict__ vW, const float* __restrict__ vb,
    float* __restrict__ out)
{
    int idx = blockIdx.x * 256 + threadIdx.x; // 2*64*512
    int half = idx >> 15;
    int j = idx & 32767;
    int r = j >> 9, c = j & 511;
    const float* W = half ? vW : muW;
    const float* bb = half ? vb : mub;
    const float4* lv = (const float4*)(latent + (size_t)r * LATD);
    const float4* wv = (const float4*)(W + (size_t)c * LATD);
    float acc = 0.f;
#pragma unroll 4
    for (int k = 0; k < LATD / 4; k++) {
        float4 a = lv[k], w = wv[k];
        acc += a.x * w.x + a.y * w.y + a.z * w.z + a.w * w.w;
    }
    out[idx] = acc + bb[c];
}

// ---------------- launch ----------------
static inline size_t align16(size_t x) { return (x + 15) & ~(size_t)15; }

extern "C" void kernel_launch(void* const* d_in, const int* in_sizes, int n_in,
                              void* d_out, int out_size, void* d_ws, size_t ws_size,
                              hipStream_t stream)
{
    const float* sfeat = (const float*)d_in[0];
    const float* bfeat = (const float*)d_in[1];
    const float* smask = (const float*)d_in[2];
    const float* bmask = (const float*)d_in[3];
    const int*   ei    = (const int*)d_in[4];
    const int*   batch = (const int*)d_in[5];
    const float* sW = (const float*)d_in[6];
    const float* sb = (const float*)d_in[7];
    const float* bW = (const float*)d_in[8];
    const float* bb = (const float*)d_in[9];
    const float* W1 = (const float*)d_in[10];
    const float* as1 = (const float*)d_in[11];
    const float* ad1 = (const float*)d_in[12];
    const float* b1 = (const float*)d_in[13];
    const float* W2 = (const float*)d_in[14];
    const float* as2 = (const float*)d_in[15];
    const float* ad2 = (const float*)d_in[16];
    const float* b2 = (const float*)d_in[17];
    const float* W3 = (const float*)d_in[18];
    const float* as3 = (const float*)d_in[19];
    const float* ad3 = (const float*)d_in[20];
    const float* b3 = (const float*)d_in[21];
    const float* aggW = (const float*)d_in[22];
    const float* aggb = (const float*)d_in[23];
    const float* muW = (const float*)d_in[24];
    const float* mub = (const float*)d_in[25];
    const float* vW = (const float*)d_in[26];
    const float* vb = (const float*)d_in[27];
    float* out = (float*)d_out;

    char* ws = (char*)d_ws;
    size_t off = 0;
    float* n0 = (float*)(ws + off); off = align16(off + (size_t)NNODES * FDIM * 4);
    float* h  = (float*)(ws + off); off = align16(off + (size_t)NNODES * HF * 4);
    float* xA = (float*)(ws + off); off = align16(off + (size_t)NNODES * HF * 4);
    unsigned short* Ahi = (unsigned short*)(ws + off); off = align16(off + (size_t)MPAD * HF * 2);
    unsigned short* Alo = (unsigned short*)(ws + off); off = align16(off + (size_t)MPAD * HF * 2);
    float* s  = (float*)(ws + off); off = align16(off + (size_t)NNODES * NHEAD * 4);
    float* d  = (float*)(ws + off); off = align16(off + (size_t)NNODES * NHEAD * 4);
    int* offs = (int*)(ws + off);   off = align16(off + (size_t)(NNODES + 1) * 4);
    int* cnt  = (int*)(ws + off);   off = align16(off + (size_t)NNODES * 4);
    int* csr  = (int*)(ws + off);   off = align16(off + (size_t)NEP * 4);
    float* g  = (float*)(ws + off); off = align16(off + (size_t)NGR * AGGIN * 4);
    float* lat = (float*)(ws + off); off = align16(off + (size_t)NGR * LATD * 4);
    unsigned short* W1hi = (unsigned short*)(ws + off); off = align16(off + (size_t)HF * FDIM * 2);
    unsigned short* W1lo = (unsigned short*)(ws + off); off = align16(off + (size_t)HF * FDIM * 2);
    unsigned short* W2hi = (unsigned short*)(ws + off); off = align16(off + (size_t)HF * HF * 2);
    unsigned short* W2lo = (unsigned short*)(ws + off); off = align16(off + (size_t)HF * HF * 2);
    unsigned short* W3hi = (unsigned short*)(ws + off); off = align16(off + (size_t)HF * HF * 2);
    unsigned short* W3lo = (unsigned short*)(ws + off); off = align16(off + (size_t)HF * HF * 2);

    const int edgeBlocks = (NEP + 255) / 256;
    const int gemmBlocks = (NNODES + 63) / 64;   // 313

    // CSR build
    hipMemsetAsync(cnt, 0, (size_t)NNODES * 4, stream);
    count_deg<<<edgeBlocks, 256, 0, stream>>>(ei, cnt);
    scan_deg<<<1, 256, 0, stream>>>(cnt, offs);
    hipMemsetAsync(cnt, 0, (size_t)NNODES * 4, stream);
    scatter_edges<<<edgeBlocks, 256, 0, stream>>>(ei, offs, cnt, csr);

    // g starts at 0 (all pooled values >= 0)
    hipMemsetAsync(g, 0, (size_t)NGR * AGGIN * 4, stream);

    // weight splits
    convert_w<<<(HF * FDIM + 255) / 256, 256, 0, stream>>>(W1, W1hi, W1lo, HF * FDIM);
    convert_w<<<(HF * HF + 255) / 256, 256, 0, stream>>>(W2, W2hi, W2lo, HF * HF);
    convert_w<<<(HF * HF + 255) / 256, 256, 0, stream>>>(W3, W3hi, W3lo, HF * HF);

    // node encoder (+ bf16 hi/lo, ld 64)
    encode_n0<<<NNODES / 32, 256, 0, stream>>>(
        sfeat, bfeat, smask, bmask, sW, sb, bW, bb, n0, Ahi, Alo);
    seg_max_slab<FDIM><<<(NNODES + 255) / 256, 256, 0, stream>>>(n0, batch, (int*)g, 0);

    // layer 1
    gemm_attn_mfma<FDIM><<<gemmBlocks, 256, 0, stream>>>(Ahi, Alo, W1hi, W1lo, as1, ad1, h, s, d);
    gat_aggr<<<NNODES / 4, 256, 0, stream>>>(h, s, d, offs, csr, b1, xA, Ahi, Alo);
    seg_max_slab<HF><<<(NNODES + 63) / 64, 256, 0, stream>>>(xA, batch, (int*)g, FDIM);

    // layer 2
    gemm_attn_mfma<HF><<<gemmBlocks, 256, 0, stream>>>(Ahi, Alo, W2hi, W2lo, as2, ad2, h, s, d);
    gat_aggr<<<NNODES / 4, 256, 0, stream>>>(h, s, d, offs, csr, b2, xA, Ahi, Alo);
    seg_max_slab<HF><<<(NNODES + 63) / 64, 256, 0, stream>>>(xA, batch, (int*)g, FDIM + HF);

    // layer 3
    gemm_attn_mfma<HF><<<gemmBlocks, 256, 0, stream>>>(Ahi, Alo, W3hi, W3lo, as3, ad3, h, s, d);
    gat_aggr<<<NNODES / 4, 256, 0, stream>>>(h, s, d, offs, csr, b3, xA, (unsigned short*)nullptr, (unsigned short*)nullptr);
    seg_max_slab<HF><<<(NNODES + 63) / 64, 256, 0, stream>>>(xA, batch, (int*)g, FDIM + 2 * HF);

    // MLP head
    mlp_latent<<<(NGR * LATD + 255) / 256, 256, 0, stream>>>(g, aggW, aggb, lat);
    mlp_head<<<(2 * NGR * LATD + 255) / 256, 256, 0, stream>>>(lat, muW, mub, vW, vb, out);
}

// Round 4
// 507.992 us; speedup vs baseline: 2.0998x; 1.1279x over previous
//
#include <hip/hip_runtime.h>
#include <math.h>

#define NNODES 20000
#define NEDGES 320000
#define FDIM 64
#define NHEAD 4
#define NGR 64
#define LATD 512
#define HF 256                // NHEAD*FDIM
#define NEP (NEDGES + NNODES) // edges incl. self loops = 340000
#define AGGIN 832             // FDIM*(1+3*NHEAD)
#define MPAD 20032            // 313*64 node padding for 64-row gemm blocks

typedef float f32x4 __attribute__((ext_vector_type(4)));
typedef short bf16x8 __attribute__((ext_vector_type(8)));

__device__ inline unsigned short f2bf(float f) {
    unsigned u = __float_as_uint(f);
    unsigned r = (u + 0x7FFF + ((u >> 16) & 1)) >> 16; // RNE
    return (unsigned short)r;
}
__device__ inline float bf2f(unsigned short h) {
    return __uint_as_float(((unsigned)h) << 16);
}
__device__ inline unsigned short f2h(float f) {
    _Float16 h = (_Float16)f;
    unsigned short u;
    __builtin_memcpy(&u, &h, 2);
    return u;
}
__device__ inline float h2f(unsigned short u) {
    _Float16 h;
    __builtin_memcpy(&h, &u, 2);
    return (float)h;
}

// ---------------- all three weight splits in one kernel ----------------
__global__ __launch_bounds__(256) void convert_w3(
    const float* __restrict__ W1, const float* __restrict__ W2, const float* __restrict__ W3,
    unsigned short* __restrict__ W1hi, unsigned short* __restrict__ W1lo,
    unsigned short* __restrict__ W2hi, unsigned short* __restrict__ W2lo,
    unsigned short* __restrict__ W3hi, unsigned short* __restrict__ W3lo)
{
    int i = blockIdx.x * 256 + threadIdx.x;
    const int n1 = HF * FDIM, n2 = HF * HF;
    const float* src; unsigned short *hi, *lo; int j;
    if (i < n1) { src = W1; hi = W1hi; lo = W1lo; j = i; }
    else if (i < n1 + n2) { src = W2; hi = W2hi; lo = W2lo; j = i - n1; }
    else if (i < n1 + 2 * n2) { src = W3; hi = W3hi; lo = W3lo; j = i - n1 - n2; }
    else return;
    float f = src[j];
    unsigned short h = f2bf(f);
    hi[j] = h;
    lo[j] = f2bf(f - bf2f(h));
}

// ---------------- encode + fused per-graph seg-max of n0 ----------------
// Emits only bf16 hi/lo of n0 (ld 64); fp32 n0 never materialized.
__global__ __launch_bounds__(256) void encode_n0(
    const float* __restrict__ sfeat, const float* __restrict__ bfeat,
    const float* __restrict__ smask, const float* __restrict__ bmask,
    const float* __restrict__ sW, const float* __restrict__ sb,
    const float* __restrict__ bW, const float* __restrict__ bb,
    const int* __restrict__ batch,
    unsigned short* __restrict__ nhi, unsigned short* __restrict__ nlo,
    int* __restrict__ g)
{
    __shared__ float wlds[64 * 132];
    int t = threadIdx.x;
#pragma unroll
    for (int it = 0; it < 8; it++) {
        int idx = it * 256 + t;
        int f = idx >> 5, k4 = idx & 31;
        float4 v = *(const float4*)(sW + f * 128 + k4 * 4);
        *(float4*)(&wlds[f * 132 + k4 * 4]) = v;
    }
    __syncthreads();

    int lane = t & 63, wave = t >> 6;
    int nb = blockIdx.x * 32 + wave * 8;

    float acc[8];
#pragma unroll
    for (int i = 0; i < 8; i++) acc[i] = 0.f;

    const float* xbase = sfeat + (size_t)nb * 128;
    for (int k4 = 0; k4 < 32; k4++) {
        float4 wv = *(const float4*)(&wlds[lane * 132 + k4 * 4]);
#pragma unroll
        for (int i = 0; i < 8; i++) {
            float4 xv = *(const float4*)(xbase + i * 128 + k4 * 4);
            acc[i] += xv.x * wv.x + xv.y * wv.y + xv.z * wv.z + xv.w * wv.w;
        }
    }

    float bwr[5];
#pragma unroll
    for (int k = 0; k < 5; k++) bwr[k] = bW[lane * 5 + k];
    float sbv = sb[lane], bbv = bb[lane];

    int curb = batch[nb];
    float m = 0.f;
#pragma unroll
    for (int i = 0; i < 8; i++) {
        int node = nb + i;
        float accb = 0.f;
#pragma unroll
        for (int k = 0; k < 5; k++) accb += bfeat[node * 5 + k] * bwr[k];
        float sv = fmaxf(acc[i] + sbv, 0.f);
        float bv = fmaxf(accb + bbv, 0.f);
        float val = sv * smask[node] + bv * bmask[node];
        unsigned short hb = f2bf(val);
        nhi[(size_t)node * FDIM + lane] = hb;
        nlo[(size_t)node * FDIM + lane] = f2bf(val - bf2f(hb));
        int b = batch[node];
        if (b != curb) {
            atomicMax(&g[curb * AGGIN + lane], __float_as_int(m));
            m = 0.f; curb = b;
        }
        m = fmaxf(m, val);
    }
    atomicMax(&g[curb * AGGIN + lane], __float_as_int(m));
}

// ---------------- CSR build ----------------
__global__ void count_deg(const int* __restrict__ ei, int* __restrict__ cnt)
{
    int i = blockIdx.x * 256 + threadIdx.x;
    if (i < NEDGES) {
        atomicAdd(&cnt[ei[NEDGES + i]], 1);
    } else if (i < NEP) {
        atomicAdd(&cnt[i - NEDGES], 1); // self loop
    }
}

__global__ __launch_bounds__(256) void scan_deg(const int* __restrict__ deg, int* __restrict__ offs)
{
    __shared__ int wt[4];
    const int per = (NNODES + 255) / 256; // 79
    int t = threadIdx.x, lane = t & 63, w = t >> 6;
    int start = t * per;
    int end = start + per; if (end > NNODES) end = NNODES;
    int s = 0;
    for (int i = start; i < end; i++) s += deg[i];
    // 64-lane inclusive shfl scan
    int pref = s;
#pragma unroll
    for (int m = 1; m < 64; m <<= 1) {
        int v = __shfl_up(pref, m, 64);
        if (lane >= m) pref += v;
    }
    if (lane == 63) wt[w] = pref;
    __syncthreads();
    int wadd = 0;
    for (int i = 0; i < w; i++) wadd += wt[i];
    int acc = wadd + pref - s; // exclusive prefix
    for (int i = start; i < end; i++) { offs[i] = acc; acc += deg[i]; }
    if (t == 255) offs[NNODES] = NEP;
}

__global__ void scatter_edges(const int* __restrict__ ei, const int* __restrict__ offs,
                              int* __restrict__ cnt, int* __restrict__ csr_src)
{
    int i = blockIdx.x * 256 + threadIdx.x;
    if (i < NEDGES) {
        int dv = ei[NEDGES + i];
        int p = offs[dv] + atomicAdd(&cnt[dv], 1);
        csr_src[p] = ei[i];
    } else if (i < NEP) {
        int nv = i - NEDGES;
        int p = offs[nv] + atomicAdd(&cnt[nv], 1);
        csr_src[p] = nv;
    }
}

// ---------------- MFMA GEMM + attention projections (bf16x3, no LDS) ----------
// All A/B fragments loaded directly from global (W is L2-resident; every
// fragment load = 16 rows x 64B coalesced). No barriers -> compiler pipelines
// next-chunk loads under the MFMAs. h written as fp16.
template <int K>
__global__ __launch_bounds__(256) void gemm_attn_mfma(
    const unsigned short* __restrict__ xhi, const unsigned short* __restrict__ xlo,
    const unsigned short* __restrict__ Whi, const unsigned short* __restrict__ Wlo,
    const float* __restrict__ a_src, const float* __restrict__ a_dst,
    unsigned short* __restrict__ h, float* __restrict__ s, float* __restrict__ d)
{
    int t = threadIdx.x, lane = t & 63, w = t >> 6;
    int colid = lane & 15, quad = lane >> 4;
    int nb = blockIdx.x * 64;

    f32x4 acc[4][4];
#pragma unroll
    for (int mt = 0; mt < 4; mt++)
#pragma unroll
        for (int nt = 0; nt < 4; nt++)
#pragma unroll
            for (int r = 0; r < 4; r++) acc[mt][nt][r] = 0.f;

    for (int kc = 0; kc < K; kc += 32) {
        bf16x8 bhi[4], blo[4], ahi[4], alo[4];
#pragma unroll
        for (int nt = 0; nt < 4; nt++) {
            size_t boff = (size_t)(w * 64 + nt * 16 + colid) * K + kc + quad * 8;
            bhi[nt] = *(const bf16x8*)&Whi[boff];
            blo[nt] = *(const bf16x8*)&Wlo[boff];
        }
#pragma unroll
        for (int mt = 0; mt < 4; mt++) {
            size_t aoff = (size_t)(nb + mt * 16 + colid) * K + kc + quad * 8;
            ahi[mt] = *(const bf16x8*)&xhi[aoff];
            alo[mt] = *(const bf16x8*)&xlo[aoff];
        }
#pragma unroll
        for (int mt = 0; mt < 4; mt++)
#pragma unroll
            for (int nt = 0; nt < 4; nt++) {
                acc[mt][nt] = __builtin_amdgcn_mfma_f32_16x16x32_bf16(ahi[mt], bhi[nt], acc[mt][nt], 0, 0, 0);
                acc[mt][nt] = __builtin_amdgcn_mfma_f32_16x16x32_bf16(ahi[mt], blo[nt], acc[mt][nt], 0, 0, 0);
                acc[mt][nt] = __builtin_amdgcn_mfma_f32_16x16x32_bf16(alo[mt], bhi[nt], acc[mt][nt], 0, 0, 0);
            }
    }

    // ---- write h (fp16): C/D layout row=quad*4+r (node), col=colid ----
#pragma unroll
    for (int mt = 0; mt < 4; mt++) {
#pragma unroll
        for (int r = 0; r < 4; r++) {
            int node = nb + mt * 16 + quad * 4 + r;
            if (node < NNODES) {
#pragma unroll
                for (int nt = 0; nt < 4; nt++)
                    h[(size_t)node * HF + w * 64 + nt * 16 + colid] = f2h(acc[mt][nt][r]);
            }
        }
    }

    // ---- attention projections for head w ----
    float as_r[4], ad_r[4];
#pragma unroll
    for (int nt = 0; nt < 4; nt++) {
        as_r[nt] = a_src[w * 64 + nt * 16 + colid];
        ad_r[nt] = a_dst[w * 64 + nt * 16 + colid];
    }
#pragma unroll
    for (int mt = 0; mt < 4; mt++) {
#pragma unroll
        for (int r = 0; r < 4; r++) {
            float ps = 0.f, pd = 0.f;
#pragma unroll
            for (int nt = 0; nt < 4; nt++) {
                ps += acc[mt][nt][r] * as_r[nt];
                pd += acc[mt][nt][r] * ad_r[nt];
            }
#pragma unroll
            for (int m = 1; m < 16; m <<= 1) {
                ps += __shfl_xor(ps, m, 64);
                pd += __shfl_xor(pd, m, 64);
            }
            if (colid == 0) {
                int node = nb + mt * 16 + quad * 4 + r;
                if (node < NNODES) {
                    s[(size_t)node * NHEAD + w] = ps;
                    d[(size_t)node * NHEAD + w] = pd;
                }
            }
        }
    }
}

// ---------------- GAT softmax + aggregate (one wave per node) ----------------
// h is fp16 (convex-combination input: fp16 rounding only). Phase-B gather
// unrolled 4x: 4 independent 8B row-loads in flight per iteration.
__global__ __launch_bounds__(256) void gat_aggr(
    const unsigned short* __restrict__ h, const float* __restrict__ s, const float* __restrict__ d,
    const int* __restrict__ offs, const int* __restrict__ csr_src,
    const float* __restrict__ bias, float* __restrict__ out,
    unsigned short* __restrict__ ohi, unsigned short* __restrict__ olo)
{
    int t = threadIdx.x;
    int lane = t & 63;
    int wv = t >> 6;
    int node = blockIdx.x * 4 + wv;
    int head4 = lane >> 4;   // phase-B head
    int lo = offs[node], hi = offs[node + 1];
    int deg = hi - lo;

    float a0 = 0.f, a1 = 0.f, a2 = 0.f, a3 = 0.f;
    float inv;

    if (deg <= 64) {
        int slot = lane >> 2, hd = lane & 3;
        float dn = d[(size_t)node * NHEAD + hd];
        float ev[4];
        int sv[4];
#pragma unroll
        for (int c = 0; c < 4; c++) {
            int k = c * 16 + slot;
            float e = -3.402823466e38f;
            int src = 0;
            if (k < deg) {
                src = csr_src[lo + k];
                float ee = s[(size_t)src * NHEAD + hd] + dn;
                e = fmaxf(ee, 0.2f * ee);
            }
            ev[c] = e; sv[c] = src;
        }
        float mx = fmaxf(fmaxf(ev[0], ev[1]), fmaxf(ev[2], ev[3]));
#pragma unroll
        for (int m = 4; m < 64; m <<= 1) mx = fmaxf(mx, __shfl_xor(mx, m, 64));
        float den = 0.f;
#pragma unroll
        for (int c = 0; c < 4; c++) {
            ev[c] = __expf(ev[c] - mx);  // invalid slots -> 0
            den += ev[c];
        }
#pragma unroll
        for (int m = 4; m < 64; m <<= 1) den += __shfl_xor(den, m, 64);

        inv = 1.f / __shfl(den, head4);

        // phase B: feature-parallel gather, 4 loads in flight
#pragma unroll
        for (int c = 0; c < 4; c++) {
            int base = c * 16;
            if (base >= deg) break;
            int n16 = deg - base; if (n16 > 16) n16 = 16;
            for (int kk = 0; kk < n16; kk += 4) {
                float ex[4]; int sr[4]; ushort4 hv[4];
#pragma unroll
                for (int u = 0; u < 4; u++) {
                    ex[u] = __shfl(ev[c], (kk + u) * 4 + head4); // 0 beyond deg
                    sr[u] = __shfl(sv[c], (kk + u) * 4 + head4); // 0 beyond deg
                }
#pragma unroll
                for (int u = 0; u < 4; u++)
                    hv[u] = *(const ushort4*)(h + (size_t)sr[u] * HF + lane * 4);
#pragma unroll
                for (int u = 0; u < 4; u++) {
                    a0 += ex[u] * h2f(hv[u].x);
                    a1 += ex[u] * h2f(hv[u].y);
                    a2 += ex[u] * h2f(hv[u].z);
                    a3 += ex[u] * h2f(hv[u].w);
                }
            }
        }
    } else {
        // fallback: serial two-pass (deg > 64; astronomically rare, exact)
        float dn = d[(size_t)node * NHEAD + head4];
        float mx = -3.402823466e38f;
        for (int i = lo; i < hi; i++) {
            int src = csr_src[i];
            float e = s[(size_t)src * NHEAD + head4] + dn;
            e = fmaxf(e, 0.2f * e);
            mx = fmaxf(mx, e);
        }
        float den = 0.f;
        for (int i = lo; i < hi; i++) {
            int src = csr_src[i];
            float e = s[(size_t)src * NHEAD + head4] + dn;
            e = fmaxf(e, 0.2f * e);
            float ex = __expf(e - mx);
            den += ex;
            ushort4 hv = *(const ushort4*)(h + (size_t)src * HF + lane * 4);
            a0 += ex * h2f(hv.x); a1 += ex * h2f(hv.y);
            a2 += ex * h2f(hv.z); a3 += ex * h2f(hv.w);
        }
        inv = 1.f / den;
    }

    int o0 = lane * 4;
    float4 r;
    r.x = fmaxf(a0 * inv + bias[o0 + 0], 0.f);
    r.y = fmaxf(a1 * inv + bias[o0 + 1], 0.f);
    r.z = fmaxf(a2 * inv + bias[o0 + 2], 0.f);
    r.w = fmaxf(a3 * inv + bias[o0 + 3], 0.f);
    *(float4*)(out + (size_t)node * HF + o0) = r;

    if (ohi) {
        ushort4 hb, lb;
        hb.x = f2bf(r.x); lb.x = f2bf(r.x - bf2f(hb.x));
        hb.y = f2bf(r.y); lb.y = f2bf(r.y - bf2f(hb.y));
        hb.z = f2bf(r.z); lb.z = f2bf(r.z - bf2f(hb.z));
        hb.w = f2bf(r.w); lb.w = f2bf(r.w - bf2f(hb.w));
        *(ushort4*)(ohi + (size_t)node * HF + o0) = hb;
        *(ushort4*)(olo + (size_t)node * HF + o0) = lb;
    }
}

// ---------------- per-graph segment max, slab-parallel atomic version ----------
template <int C>
__global__ __launch_bounds__(256) void seg_max_slab(
    const float* __restrict__ x, const int* __restrict__ batch,
    int* __restrict__ g, int coloff)
{
    constexpr int TEAMS = 256 / C;
    constexpr int ROWS = 64;
    int team = threadIdx.x / C;
    int f = threadIdx.x % C;
    int r0 = (blockIdx.x * TEAMS + team) * ROWS;
    if (r0 >= NNODES) return;
    int r1 = r0 + ROWS; if (r1 > NNODES) r1 = NNODES;
    int cur = batch[r0];
    float m = 0.f;
    for (int r = r0; r < r1; r++) {
        int b = batch[r];
        if (b != cur) {
            atomicMax(&g[cur * AGGIN + coloff + f], __float_as_int(m));
            m = 0.f; cur = b;
        }
        m = fmaxf(m, x[(size_t)r * C + f]);
    }
    atomicMax(&g[cur * AGGIN + coloff + f], __float_as_int(m));
}

// ---------------- MLP head ----------------
__global__ __launch_bounds__(256) void mlp_latent(
    const float* __restrict__ g, const float* __restrict__ W, const float* __restrict__ b,
    float* __restrict__ latent)
{
    int idx = blockIdx.x * 256 + threadIdx.x; // 64*512
    int r = idx >> 9, c = idx & 511;
    const float4* gv = (const float4*)(g + (size_t)r * AGGIN);
    const float4* wv = (const float4*)(W + (size_t)c * AGGIN);
    float acc = 0.f;
#pragma unroll 4
    for (int k = 0; k < AGGIN / 4; k++) {
        float4 a = gv[k], w = wv[k];
        acc += a.x * w.x + a.y * w.y + a.z * w.z + a.w * w.w;
    }
    latent[idx] = acc + b[c];
}

__global__ __launch_bounds__(256) void mlp_head(
    const float* __restrict__ latent,
    const float* __restrict__ muW, const float* __restrict__ mub,
    const float* __restrict__ vW, const float* __restrict__ vb,
    float* __restrict__ out)
{
    int idx = blockIdx.x * 256 + threadIdx.x; // 2*64*512
    int half = idx >> 15;
    int j = idx & 32767;
    int r = j >> 9, c = j & 511;
    const float* W = half ? vW : muW;
    const float* bb = half ? vb : mub;
    const float4* lv = (const float4*)(latent + (size_t)r * LATD);
    const float4* wv = (const float4*)(W + (size_t)c * LATD);
    float acc = 0.f;
#pragma unroll 4
    for (int k = 0; k < LATD / 4; k++) {
        float4 a = lv[k], w = wv[k];
        acc += a.x * w.x + a.y * w.y + a.z * w.z + a.w * w.w;
    }
    out[idx] = acc + bb[c];
}

// ---------------- launch ----------------
static inline size_t align16(size_t x) { return (x + 15) & ~(size_t)15; }

extern "C" void kernel_launch(void* const* d_in, const int* in_sizes, int n_in,
                              void* d_out, int out_size, void* d_ws, size_t ws_size,
                              hipStream_t stream)
{
    const float* sfeat = (const float*)d_in[0];
    const float* bfeat = (const float*)d_in[1];
    const float* smask = (const float*)d_in[2];
    const float* bmask = (const float*)d_in[3];
    const int*   ei    = (const int*)d_in[4];
    const int*   batch = (const int*)d_in[5];
    const float* sW = (const float*)d_in[6];
    const float* sb = (const float*)d_in[7];
    const float* bW = (const float*)d_in[8];
    const float* bb = (const float*)d_in[9];
    const float* W1 = (const float*)d_in[10];
    const float* as1 = (const float*)d_in[11];
    const float* ad1 = (const float*)d_in[12];
    const float* b1 = (const float*)d_in[13];
    const float* W2 = (const float*)d_in[14];
    const float* as2 = (const float*)d_in[15];
    const float* ad2 = (const float*)d_in[16];
    const float* b2 = (const float*)d_in[17];
    const float* W3 = (const float*)d_in[18];
    const float* as3 = (const float*)d_in[19];
    const float* ad3 = (const float*)d_in[20];
    const float* b3 = (const float*)d_in[21];
    const float* aggW = (const float*)d_in[22];
    const float* aggb = (const float*)d_in[23];
    const float* muW = (const float*)d_in[24];
    const float* mub = (const float*)d_in[25];
    const float* vW = (const float*)d_in[26];
    const float* vb = (const float*)d_in[27];
    float* out = (float*)d_out;

    char* ws = (char*)d_ws;
    size_t off = 0;
    unsigned short* h = (unsigned short*)(ws + off); off = align16(off + (size_t)NNODES * HF * 2);
    float* xA = (float*)(ws + off); off = align16(off + (size_t)NNODES * HF * 4);
    unsigned short* Ahi = (unsigned short*)(ws + off); off = align16(off + (size_t)MPAD * HF * 2);
    unsigned short* Alo = (unsigned short*)(ws + off); off = align16(off + (size_t)MPAD * HF * 2);
    float* s  = (float*)(ws + off); off = align16(off + (size_t)NNODES * NHEAD * 4);
    float* d  = (float*)(ws + off); off = align16(off + (size_t)NNODES * NHEAD * 4);
    int* offs = (int*)(ws + off);   off = align16(off + (size_t)(NNODES + 1) * 4);
    int* cnt  = (int*)(ws + off);   off = align16(off + (size_t)NNODES * 4);
    int* csr  = (int*)(ws + off);   off = align16(off + (size_t)NEP * 4);
    float* g  = (float*)(ws + off); off = align16(off + (size_t)NGR * AGGIN * 4);
    float* lat = (float*)(ws + off); off = align16(off + (size_t)NGR * LATD * 4);
    unsigned short* W1hi = (unsigned short*)(ws + off); off = align16(off + (size_t)HF * FDIM * 2);
    unsigned short* W1lo = (unsigned short*)(ws + off); off = align16(off + (size_t)HF * FDIM * 2);
    unsigned short* W2hi = (unsigned short*)(ws + off); off = align16(off + (size_t)HF * HF * 2);
    unsigned short* W2lo = (unsigned short*)(ws + off); off = align16(off + (size_t)HF * HF * 2);
    unsigned short* W3hi = (unsigned short*)(ws + off); off = align16(off + (size_t)HF * HF * 2);
    unsigned short* W3lo = (unsigned short*)(ws + off); off = align16(off + (size_t)HF * HF * 2);

    const int edgeBlocks = (NEP + 255) / 256;
    const int gemmBlocks = (NNODES + 63) / 64;   // 313

    // CSR build
    hipMemsetAsync(cnt, 0, (size_t)NNODES * 4, stream);
    count_deg<<<edgeBlocks, 256, 0, stream>>>(ei, cnt);
    scan_deg<<<1, 256, 0, stream>>>(cnt, offs);
    hipMemsetAsync(cnt, 0, (size_t)NNODES * 4, stream);
    scatter_edges<<<edgeBlocks, 256, 0, stream>>>(ei, offs, cnt, csr);

    // g starts at 0 (all pooled values >= 0)
    hipMemsetAsync(g, 0, (size_t)NGR * AGGIN * 4, stream);

    // weight splits (one kernel)
    convert_w3<<<(HF * FDIM + 2 * HF * HF + 255) / 256, 256, 0, stream>>>(
        W1, W2, W3, W1hi, W1lo, W2hi, W2lo, W3hi, W3lo);

    // node encoder (+ bf16 hi/lo, ld 64, + fused n0 seg-max)
    encode_n0<<<NNODES / 32, 256, 0, stream>>>(
        sfeat, bfeat, smask, bmask, sW, sb, bW, bb, batch, Ahi, Alo, (int*)g);

    // layer 1
    gemm_attn_mfma<FDIM><<<gemmBlocks, 256, 0, stream>>>(Ahi, Alo, W1hi, W1lo, as1, ad1, h, s, d);
    gat_aggr<<<NNODES / 4, 256, 0, stream>>>(h, s, d, offs, csr, b1, xA, Ahi, Alo);
    seg_max_slab<HF><<<(NNODES + 63) / 64, 256, 0, stream>>>(xA, batch, (int*)g, FDIM);

    // layer 2
    gemm_attn_mfma<HF><<<gemmBlocks, 256, 0, stream>>>(Ahi, Alo, W2hi, W2lo, as2, ad2, h, s, d);
    gat_aggr<<<NNODES / 4, 256, 0, stream>>>(h, s, d, offs, csr, b2, xA, Ahi, Alo);
    seg_max_slab<HF><<<(NNODES + 63) / 64, 256, 0, stream>>>(xA, batch, (int*)g, FDIM + HF);

    // layer 3
    gemm_attn_mfma<HF><<<gemmBlocks, 256, 0, stream>>>(Ahi, Alo, W3hi, W3lo, as3, ad3, h, s, d);
    gat_aggr<<<NNODES / 4, 256, 0, stream>>>(h, s, d, offs, csr, b3, xA, (unsigned short*)nullptr, (unsigned short*)nullptr);
    seg_max_slab<HF><<<(NNODES + 63) / 64, 256, 0, stream>>>(xA, batch, (int*)g, FDIM + 2 * HF);

    // MLP head
    mlp_latent<<<(NGR * LATD + 255) / 256, 256, 0, stream>>>(g, aggW, aggb, lat);
    mlp_head<<<(2 * NGR * LATD + 255) / 256, 256, 0, stream>>>(lat, muW, mub, vW, vb, out);
}